// Round 6
// baseline (462.660 us; speedup 1.0000x reference)
//
#include <hip/hip_runtime.h>

#define NN 100000
#define NE 1600000

// ---- bf16 helpers (round-to-nearest-even, matches numpy/jax cast) ----
__device__ inline unsigned short f2bf(float f) {
    unsigned int u = __float_as_uint(f);
    unsigned int r = (u + 0x7fffu + ((u >> 16) & 1u)) >> 16;
    return (unsigned short)r;
}
__device__ inline float bf2f(unsigned short h) {
    return __uint_as_float(((unsigned int)h) << 16);
}
__device__ inline float bflo(unsigned int v) { return __uint_as_float(v << 16); }
__device__ inline float bfhi(unsigned int v) { return __uint_as_float(v & 0xffff0000u); }

// ---------------- CSR build ----------------

__global__ void k_deg_count(const int* __restrict__ dst, int* __restrict__ cnt, int E) {
    int e = blockIdx.x * blockDim.x + threadIdx.x;
    if (e < E) atomicAdd(&cnt[dst[e]], 1);
}

__global__ void k_dinv(const int* __restrict__ cnt, float* __restrict__ dinv, int N) {
    int i = blockIdx.x * blockDim.x + threadIdx.x;
    if (i < N) dinv[i] = rsqrtf((float)(cnt[i] + 1));  // +1 self loop
}

__global__ void k_scan1(const int* __restrict__ cnt, int* __restrict__ excl,
                        int* __restrict__ bsums, int N) {
    __shared__ int s[512];
    int tid = threadIdx.x;
    int i = blockIdx.x * 512 + tid;
    int v = (i < N) ? cnt[i] : 0;
    s[tid] = v;
    __syncthreads();
    for (int off = 1; off < 512; off <<= 1) {
        int t = (tid >= off) ? s[tid - off] : 0;
        __syncthreads();
        s[tid] += t;
        __syncthreads();
    }
    if (i < N) excl[i] = s[tid] - v;
    if (tid == 511) bsums[blockIdx.x] = s[511];
}

__global__ void k_scan2(int* __restrict__ bsums, int nb) {
    if (blockIdx.x == 0 && threadIdx.x == 0) {
        int run = 0;
        for (int b = 0; b < nb; ++b) { int t = bsums[b]; bsums[b] = run; run += t; }
    }
}

__global__ void k_scan3(int* __restrict__ row_ptr, int* __restrict__ fill_ptr,
                        const int* __restrict__ bsums, int N, int E) {
    int i = blockIdx.x * blockDim.x + threadIdx.x;
    if (i < N) {
        int v = row_ptr[i] + bsums[i >> 9];
        row_ptr[i] = v;
        fill_ptr[i] = v;
    }
    if (i == 0) row_ptr[N] = E;
}

// Persistent-block fill, 8 sequential dst-range passes for write locality:
// during pass p all col/ew writes land in a contiguous ~1/8 region -> lines
// stay L2-resident until fully written (kills the 12x write amplification).
// Pass skew across blocks only degrades locality, never correctness.
#define FILL_PASSES 8
__global__ void k_fill(const int* __restrict__ src, const int* __restrict__ dst,
                       const float* __restrict__ dinv, int* __restrict__ fill_ptr,
                       int* __restrict__ col, float* __restrict__ ew, int E, int N) {
    int nblk = gridDim.x;
    int chunk = (E + nblk - 1) / nblk;
    int e0 = blockIdx.x * chunk;
    int e1 = e0 + chunk; if (e1 > E) e1 = E;
    int rng = (N + FILL_PASSES - 1) / FILL_PASSES;
    for (int p = 0; p < FILL_PASSES; ++p) {
        int dlo = p * rng, dhi = dlo + rng;
        for (int e = e0 + threadIdx.x; e < e1; e += blockDim.x) {
            int d = dst[e];
            if (d >= dlo && d < dhi) {
                int s = src[e];
                int pos = atomicAdd(&fill_ptr[d], 1);
                col[pos] = s;
                ew[pos] = dinv[s] * dinv[d];
            }
        }
    }
}

// ---------------- f32 -> bf16 conversion (8 elems/thread) ----------------

__global__ void k_tobf16(const float* __restrict__ in, unsigned short* __restrict__ out, int n8) {
    int i = blockIdx.x * blockDim.x + threadIdx.x;
    if (i >= n8) return;
    const float4* p = (const float4*)(in + (size_t)i * 8);
    float4 a = p[0], b = p[1];
    uint4 o;
    o.x = (unsigned)f2bf(a.x) | ((unsigned)f2bf(a.y) << 16);
    o.y = (unsigned)f2bf(a.z) | ((unsigned)f2bf(a.w) << 16);
    o.z = (unsigned)f2bf(b.x) | ((unsigned)f2bf(b.y) << 16);
    o.w = (unsigned)f2bf(b.z) | ((unsigned)f2bf(b.w) << 16);
    ((uint4*)out)[i] = o;
}

// ------- aggregation: wave/node; coalesced col/ew staging + 8 gathers in flight -------

template <int C>
__global__ void k_agg(const unsigned short* __restrict__ xb, const int* __restrict__ row_ptr,
                      const int* __restrict__ col, const float* __restrict__ ew,
                      const float* __restrict__ dinv, float* __restrict__ out, int N) {
    int node = blockIdx.x * (blockDim.x >> 6) + (threadIdx.x >> 6);
    int lane = threadIdx.x & 63;
    if (node >= N) return;
    int beg = row_ptr[node], end = row_ptr[node + 1];
    float di = dinv[node];

    if constexpr (C == 64) {
        float acc = 0.f;
        for (int base = beg; base < end; base += 64) {
            int m = end - base; if (m > 64) m = 64;
            int sel = (lane < m) ? lane : (m - 1);
            int cl = col[base + sel];
            float wl = (lane < m) ? ew[base + sel] : 0.f;
            for (int k = 0; k < m; k += 8) {
                int c0 = __shfl(cl, k),     c1 = __shfl(cl, k + 1);
                int c2 = __shfl(cl, k + 2), c3 = __shfl(cl, k + 3);
                int c4 = __shfl(cl, k + 4), c5 = __shfl(cl, k + 5);
                int c6 = __shfl(cl, k + 6), c7 = __shfl(cl, k + 7);
                float w0 = __shfl(wl, k),     w1 = __shfl(wl, k + 1);
                float w2 = __shfl(wl, k + 2), w3 = __shfl(wl, k + 3);
                float w4 = __shfl(wl, k + 4), w5 = __shfl(wl, k + 5);
                float w6 = __shfl(wl, k + 6), w7 = __shfl(wl, k + 7);
                unsigned short v0 = xb[(size_t)c0 * 64 + lane];
                unsigned short v1 = xb[(size_t)c1 * 64 + lane];
                unsigned short v2 = xb[(size_t)c2 * 64 + lane];
                unsigned short v3 = xb[(size_t)c3 * 64 + lane];
                unsigned short v4 = xb[(size_t)c4 * 64 + lane];
                unsigned short v5 = xb[(size_t)c5 * 64 + lane];
                unsigned short v6 = xb[(size_t)c6 * 64 + lane];
                unsigned short v7 = xb[(size_t)c7 * 64 + lane];
                acc += w0 * bf2f(v0) + w1 * bf2f(v1) + w2 * bf2f(v2) + w3 * bf2f(v3)
                     + w4 * bf2f(v4) + w5 * bf2f(v5) + w6 * bf2f(v6) + w7 * bf2f(v7);
            }
        }
        acc += di * di * bf2f(xb[(size_t)node * 64 + lane]);
        out[(size_t)node * 64 + lane] = acc;
    } else {
        const unsigned int* xb2 = (const unsigned int*)xb;  // 2 bf16 per uint
        float ax = 0.f, ay = 0.f;
        for (int base = beg; base < end; base += 64) {
            int m = end - base; if (m > 64) m = 64;
            int sel = (lane < m) ? lane : (m - 1);
            int cl = col[base + sel];
            float wl = (lane < m) ? ew[base + sel] : 0.f;
            for (int k = 0; k < m; k += 8) {
                int c0 = __shfl(cl, k),     c1 = __shfl(cl, k + 1);
                int c2 = __shfl(cl, k + 2), c3 = __shfl(cl, k + 3);
                int c4 = __shfl(cl, k + 4), c5 = __shfl(cl, k + 5);
                int c6 = __shfl(cl, k + 6), c7 = __shfl(cl, k + 7);
                float w0 = __shfl(wl, k),     w1 = __shfl(wl, k + 1);
                float w2 = __shfl(wl, k + 2), w3 = __shfl(wl, k + 3);
                float w4 = __shfl(wl, k + 4), w5 = __shfl(wl, k + 5);
                float w6 = __shfl(wl, k + 6), w7 = __shfl(wl, k + 7);
                unsigned int v0 = xb2[(size_t)c0 * 64 + lane];
                unsigned int v1 = xb2[(size_t)c1 * 64 + lane];
                unsigned int v2 = xb2[(size_t)c2 * 64 + lane];
                unsigned int v3 = xb2[(size_t)c3 * 64 + lane];
                unsigned int v4 = xb2[(size_t)c4 * 64 + lane];
                unsigned int v5 = xb2[(size_t)c5 * 64 + lane];
                unsigned int v6 = xb2[(size_t)c6 * 64 + lane];
                unsigned int v7 = xb2[(size_t)c7 * 64 + lane];
                ax += w0 * bflo(v0) + w1 * bflo(v1) + w2 * bflo(v2) + w3 * bflo(v3)
                    + w4 * bflo(v4) + w5 * bflo(v5) + w6 * bflo(v6) + w7 * bflo(v7);
                ay += w0 * bfhi(v0) + w1 * bfhi(v1) + w2 * bfhi(v2) + w3 * bfhi(v3)
                    + w4 * bfhi(v4) + w5 * bfhi(v5) + w6 * bfhi(v6) + w7 * bfhi(v7);
            }
        }
        unsigned int v = xb2[(size_t)node * 64 + lane];
        ax += di * di * bflo(v);
        ay += di * di * bfhi(v);
        *(float2*)&out[(size_t)node * 128 + 2 * lane] = make_float2(ax, ay);
    }
}

// ------- GEMM (+bias+relu): out[N,128] = A[N,K] @ W[K,128], optional bf16 out -------

template <int K, bool OUTBF>
__global__ __launch_bounds__(256) void k_gemm_relu(
    const float* __restrict__ A, const float* __restrict__ W,
    const float* __restrict__ bias, void* __restrict__ outp, int N) {
    __shared__ float Wlds[64][128];
    int tid = threadIdx.x;
    int rg = tid >> 3;   // 0..31
    int cg = tid & 7;    // 0..7 -> cols [cg*16, cg*16+16)
    int row0 = blockIdx.x * 128 + rg * 4;

    float4 acc[4][4];
#pragma unroll
    for (int i = 0; i < 4; ++i)
#pragma unroll
        for (int j = 0; j < 4; ++j) acc[i][j] = make_float4(0.f, 0.f, 0.f, 0.f);

    for (int kc = 0; kc < K; kc += 64) {
        const float4* wsrc = (const float4*)(W + (size_t)kc * 128);
        float4* wdst = (float4*)Wlds;
        for (int t = tid; t < 2048; t += 256) wdst[t] = wsrc[t];
        __syncthreads();

        for (int k4 = 0; k4 < 64; k4 += 4) {
            float4 av[4];
#pragma unroll
            for (int i = 0; i < 4; ++i) {
                int r = row0 + i;
                if (r >= N) r = N - 1;
                av[i] = *(const float4*)&A[(size_t)r * K + kc + k4];
            }
#pragma unroll
            for (int kk = 0; kk < 4; ++kk) {
                float4 w[4];
#pragma unroll
                for (int j = 0; j < 4; ++j)
                    w[j] = *(const float4*)&Wlds[k4 + kk][cg * 16 + 4 * j];
#pragma unroll
                for (int i = 0; i < 4; ++i) {
                    float a = (kk == 0) ? av[i].x : (kk == 1) ? av[i].y
                              : (kk == 2) ? av[i].z : av[i].w;
#pragma unroll
                    for (int j = 0; j < 4; ++j) {
                        acc[i][j].x += a * w[j].x;
                        acc[i][j].y += a * w[j].y;
                        acc[i][j].z += a * w[j].z;
                        acc[i][j].w += a * w[j].w;
                    }
                }
            }
        }
        __syncthreads();
    }

#pragma unroll
    for (int j = 0; j < 4; ++j) {
        float4 bv = *(const float4*)&bias[cg * 16 + 4 * j];
#pragma unroll
        for (int i = 0; i < 4; ++i) {
            int r = row0 + i;
            if (r < N) {
                float ox = fmaxf(acc[i][j].x + bv.x, 0.f);
                float oy = fmaxf(acc[i][j].y + bv.y, 0.f);
                float oz = fmaxf(acc[i][j].z + bv.z, 0.f);
                float ow = fmaxf(acc[i][j].w + bv.w, 0.f);
                if constexpr (OUTBF) {
                    ushort4 o;
                    o.x = f2bf(ox); o.y = f2bf(oy); o.z = f2bf(oz); o.w = f2bf(ow);
                    *(ushort4*)&((unsigned short*)outp)[(size_t)r * 128 + cg * 16 + 4 * j] = o;
                } else {
                    float4 o = make_float4(ox, oy, oz, ow);
                    *(float4*)&((float*)outp)[(size_t)r * 128 + cg * 16 + 4 * j] = o;
                }
            }
        }
    }
}

// ---------------- pooling ----------------

__global__ void k_cntg_bs(const int* __restrict__ batch, int* __restrict__ cntg, int N) {
    int g = threadIdx.x;
    if (g >= 64) return;
    int lo = 0, hi = N;
    while (lo < hi) { int mid = (lo + hi) >> 1; if (batch[mid] < g) lo = mid + 1; else hi = mid; }
    int start = lo;
    lo = 0; hi = N;
    while (lo < hi) { int mid = (lo + hi) >> 1; if (batch[mid] < g + 1) lo = mid + 1; else hi = mid; }
    cntg[g] = lo - start;
}

#define POOL_NPB 64
__global__ void k_pool(const float* __restrict__ h, const int* __restrict__ batch,
                       float* __restrict__ pooled, int N) {
    int tid = threadIdx.x;  // 128 threads = channel
    int start = blockIdx.x * POOL_NPB;
    int end = start + POOL_NPB;
    if (end > N) end = N;
    if (start >= end) return;
    int curg = batch[start];
    float acc = 0.f;
    for (int n = start; n < end; ++n) {
        int g = batch[n];
        if (g != curg) {
            atomicAdd(&pooled[curg * 128 + tid], acc);
            acc = 0.f;
            curg = g;
        }
        acc += h[(size_t)n * 128 + tid];
    }
    atomicAdd(&pooled[curg * 128 + tid], acc);
}

__global__ void k_final(const float* __restrict__ pooled, const int* __restrict__ cntg,
                        const float* __restrict__ Wc, const float* __restrict__ bc,
                        float* __restrict__ out) {
    for (int idx = threadIdx.x; idx < 64 * 10; idx += 256) {
        int g = idx / 10, c = idx % 10;
        float s = 0.f;
        for (int k = 0; k < 128; ++k) s += pooled[g * 128 + k] * Wc[k * 10 + c];
        float cnt = (float)cntg[g];
        if (cnt < 1.f) cnt = 1.f;
        out[idx] = s / cnt + bc[c];
    }
}

// ---------------- launch ----------------

extern "C" void kernel_launch(void* const* d_in, const int* in_sizes, int n_in,
                              void* d_out, int out_size, void* d_ws, size_t ws_size,
                              hipStream_t stream) {
    const float* x  = (const float*)d_in[0];
    const float* W1 = (const float*)d_in[1];
    const float* b1 = (const float*)d_in[2];
    const float* W2 = (const float*)d_in[3];
    const float* b2 = (const float*)d_in[4];
    const float* Wc = (const float*)d_in[5];
    const float* bc = (const float*)d_in[6];
    const int* ei   = (const int*)d_in[7];
    const int* batch = (const int*)d_in[8];

    const int E = in_sizes[7] / 2;
    const int N = in_sizes[8];
    const int* src = ei;
    const int* dst = ei + E;

    char* p = (char*)d_ws;
    auto alloc = [&](size_t bytes) -> void* {
        void* r = (void*)p;
        p += (bytes + 255) & ~(size_t)255;
        return r;
    };
    int*   cnt      = (int*)alloc((size_t)N * 4);
    float* dinv     = (float*)alloc((size_t)N * 4);
    int*   row_ptr  = (int*)alloc((size_t)(N + 1) * 4);
    int*   fill_ptr = (int*)alloc((size_t)N * 4);
    int*   bsums    = (int*)alloc(4096);
    int*   col      = (int*)alloc((size_t)E * 4);
    float* ew       = (float*)alloc((size_t)E * 4);
    unsigned short* xb  = (unsigned short*)alloc((size_t)N * 64 * 2);
    unsigned short* h1b = (unsigned short*)alloc((size_t)N * 128 * 2);
    float* bufA     = (float*)alloc((size_t)N * 128 * 4);
    float* bufB     = (float*)alloc((size_t)N * 128 * 4);
    float* pooled   = (float*)alloc(64 * 128 * 4);
    int*   cntg     = (int*)alloc(64 * 4);

    hipMemsetAsync(cnt, 0, (size_t)N * 4, stream);
    hipMemsetAsync(pooled, 0, 64 * 128 * 4, stream);

    int nb = (N + 511) / 512;

    k_deg_count<<<(E + 255) / 256, 256, 0, stream>>>(dst, cnt, E);
    k_dinv<<<(N + 255) / 256, 256, 0, stream>>>(cnt, dinv, N);
    k_scan1<<<nb, 512, 0, stream>>>(cnt, row_ptr, bsums, N);
    k_scan2<<<1, 64, 0, stream>>>(bsums, nb);
    k_scan3<<<(N + 255) / 256, 256, 0, stream>>>(row_ptr, fill_ptr, bsums, N, E);
    k_fill<<<512, 256, 0, stream>>>(src, dst, dinv, fill_ptr, col, ew, E, N);

    // x -> bf16 (gather operand for layer 1)
    k_tobf16<<<(N * 64 / 8 + 255) / 256, 256, 0, stream>>>(x, xb, N * 64 / 8);

    // layer 1: aggregate x_bf16 (64 ch) then transform; h1 written as bf16
    k_agg<64><<<(N + 3) / 4, 256, 0, stream>>>(xb, row_ptr, col, ew, dinv, bufA, N);
    k_gemm_relu<64, true><<<(N + 127) / 128, 256, 0, stream>>>(bufA, W1, b1, h1b, N);

    // layer 2: aggregate h1_bf16 (128 ch) then transform (f32 out)
    k_agg<128><<<(N + 3) / 4, 256, 0, stream>>>(h1b, row_ptr, col, ew, dinv, bufA, N);
    k_gemm_relu<128, false><<<(N + 127) / 128, 256, 0, stream>>>(bufA, W2, b2, bufB, N);

    // pool + classify
    k_cntg_bs<<<1, 64, 0, stream>>>(batch, cntg, N);
    k_pool<<<(N + POOL_NPB - 1) / POOL_NPB, 128, 0, stream>>>(bufB, batch, pooled, N);
    k_final<<<1, 256, 0, stream>>>(pooled, cntg, Wc, bc, (float*)d_out);
}

// Round 7
// 448.986 us; speedup vs baseline: 1.0305x; 1.0305x over previous
//
#include <hip/hip_runtime.h>

#define NN 100000
#define NE 1600000

// ---- bf16 helpers (round-to-nearest-even, matches numpy/jax cast) ----
__device__ inline unsigned short f2bf(float f) {
    unsigned int u = __float_as_uint(f);
    unsigned int r = (u + 0x7fffu + ((u >> 16) & 1u)) >> 16;
    return (unsigned short)r;
}
__device__ inline float bf2f(unsigned short h) {
    return __uint_as_float(((unsigned int)h) << 16);
}
__device__ inline float bflo(unsigned int v) { return __uint_as_float(v << 16); }
__device__ inline float bfhi(unsigned int v) { return __uint_as_float(v & 0xffff0000u); }

// ---------------- CSR build ----------------

__global__ void k_deg_count(const int* __restrict__ dst, int* __restrict__ cnt, int E) {
    int e = blockIdx.x * blockDim.x + threadIdx.x;
    if (e < E) atomicAdd(&cnt[dst[e]], 1);
}

__global__ void k_dinv(const int* __restrict__ cnt, float* __restrict__ dinv, int N) {
    int i = blockIdx.x * blockDim.x + threadIdx.x;
    if (i < N) dinv[i] = rsqrtf((float)(cnt[i] + 1));  // +1 self loop
}

__global__ void k_scan1(const int* __restrict__ cnt, int* __restrict__ excl,
                        int* __restrict__ bsums, int N) {
    __shared__ int s[512];
    int tid = threadIdx.x;
    int i = blockIdx.x * 512 + tid;
    int v = (i < N) ? cnt[i] : 0;
    s[tid] = v;
    __syncthreads();
    for (int off = 1; off < 512; off <<= 1) {
        int t = (tid >= off) ? s[tid - off] : 0;
        __syncthreads();
        s[tid] += t;
        __syncthreads();
    }
    if (i < N) excl[i] = s[tid] - v;
    if (tid == 511) bsums[blockIdx.x] = s[511];
}

__global__ void k_scan2(int* __restrict__ bsums, int nb) {
    if (blockIdx.x == 0 && threadIdx.x == 0) {
        int run = 0;
        for (int b = 0; b < nb; ++b) { int t = bsums[b]; bsums[b] = run; run += t; }
    }
}

__global__ void k_scan3(int* __restrict__ row_ptr, int* __restrict__ fill_ptr,
                        const int* __restrict__ bsums, int N, int E) {
    int i = blockIdx.x * blockDim.x + threadIdx.x;
    if (i < N) {
        int v = row_ptr[i] + bsums[i >> 9];
        row_ptr[i] = v;
        fill_ptr[i] = v;
    }
    if (i == 0) row_ptr[N] = E;
}

// CSR fill with XCD-spatial range ownership: block b owns dst-range (b%8) and
// edge-chunk (b/8). Consecutive blockIdx round-robins across the 8 XCDs, so
// ALL writers of a given range sit on ONE XCD; the range's ~800 KB CSR segment
// stays in that XCD's 4 MiB L2 until lines are fully written -> ~1x write amp
// (the round-6 temporal-pass scheme failed because writers spanned all XCDs).
#define FILL_RANGES 8
__global__ void k_fill(const int* __restrict__ src, const int* __restrict__ dst,
                       int* __restrict__ fill_ptr, int* __restrict__ col, int E, int N) {
    int range  = blockIdx.x & (FILL_RANGES - 1);
    int chunkI = blockIdx.x >> 3;
    int nchunk = gridDim.x >> 3;
    int per = (E + nchunk - 1) / nchunk;
    int e0 = chunkI * per;
    int e1 = e0 + per; if (e1 > E) e1 = E;
    int rng = (N + FILL_RANGES - 1) / FILL_RANGES;
    int dlo = range * rng, dhi = dlo + rng;
    for (int e = e0 + threadIdx.x; e < e1; e += blockDim.x) {
        int d = dst[e];
        if (d >= dlo && d < dhi) {
            int pos = atomicAdd(&fill_ptr[d], 1);
            col[pos] = src[e];
        }
    }
}

// ---------------- f32 -> bf16 conversion (8 elems/thread) ----------------

__global__ void k_tobf16(const float* __restrict__ in, unsigned short* __restrict__ out, int n8) {
    int i = blockIdx.x * blockDim.x + threadIdx.x;
    if (i >= n8) return;
    const float4* p = (const float4*)(in + (size_t)i * 8);
    float4 a = p[0], b = p[1];
    uint4 o;
    o.x = (unsigned)f2bf(a.x) | ((unsigned)f2bf(a.y) << 16);
    o.y = (unsigned)f2bf(a.z) | ((unsigned)f2bf(a.w) << 16);
    o.z = (unsigned)f2bf(b.x) | ((unsigned)f2bf(b.y) << 16);
    o.w = (unsigned)f2bf(b.z) | ((unsigned)f2bf(b.w) << 16);
    ((uint4*)out)[i] = o;
}

// ------- aggregation: wave/node; coalesced col staging, dinv gathered (L2-hit),
// ------- dinv[node] factored out of the sum; 8 row-gathers in flight -------

template <int C>
__global__ void k_agg(const unsigned short* __restrict__ xb, const int* __restrict__ row_ptr,
                      const int* __restrict__ col, const float* __restrict__ dinv,
                      float* __restrict__ out, int N) {
    int node = blockIdx.x * (blockDim.x >> 6) + (threadIdx.x >> 6);
    int lane = threadIdx.x & 63;
    if (node >= N) return;
    int beg = row_ptr[node], end = row_ptr[node + 1];
    float di = dinv[node];

    if constexpr (C == 64) {
        float acc = 0.f;
        for (int base = beg; base < end; base += 64) {
            int m = end - base; if (m > 64) m = 64;
            int sel = (lane < m) ? lane : (m - 1);
            int cl = col[base + sel];
            float wl = (lane < m) ? dinv[cl] : 0.f;   // w_e = dinv[src]; di factored out
            for (int k = 0; k < m; k += 8) {
                int c0 = __shfl(cl, k),     c1 = __shfl(cl, k + 1);
                int c2 = __shfl(cl, k + 2), c3 = __shfl(cl, k + 3);
                int c4 = __shfl(cl, k + 4), c5 = __shfl(cl, k + 5);
                int c6 = __shfl(cl, k + 6), c7 = __shfl(cl, k + 7);
                float w0 = __shfl(wl, k),     w1 = __shfl(wl, k + 1);
                float w2 = __shfl(wl, k + 2), w3 = __shfl(wl, k + 3);
                float w4 = __shfl(wl, k + 4), w5 = __shfl(wl, k + 5);
                float w6 = __shfl(wl, k + 6), w7 = __shfl(wl, k + 7);
                unsigned short v0 = xb[(size_t)c0 * 64 + lane];
                unsigned short v1 = xb[(size_t)c1 * 64 + lane];
                unsigned short v2 = xb[(size_t)c2 * 64 + lane];
                unsigned short v3 = xb[(size_t)c3 * 64 + lane];
                unsigned short v4 = xb[(size_t)c4 * 64 + lane];
                unsigned short v5 = xb[(size_t)c5 * 64 + lane];
                unsigned short v6 = xb[(size_t)c6 * 64 + lane];
                unsigned short v7 = xb[(size_t)c7 * 64 + lane];
                acc += w0 * bf2f(v0) + w1 * bf2f(v1) + w2 * bf2f(v2) + w3 * bf2f(v3)
                     + w4 * bf2f(v4) + w5 * bf2f(v5) + w6 * bf2f(v6) + w7 * bf2f(v7);
            }
        }
        acc = di * acc + di * di * bf2f(xb[(size_t)node * 64 + lane]);
        out[(size_t)node * 64 + lane] = acc;
    } else {
        const unsigned int* xb2 = (const unsigned int*)xb;  // 2 bf16 per uint
        float ax = 0.f, ay = 0.f;
        for (int base = beg; base < end; base += 64) {
            int m = end - base; if (m > 64) m = 64;
            int sel = (lane < m) ? lane : (m - 1);
            int cl = col[base + sel];
            float wl = (lane < m) ? dinv[cl] : 0.f;
            for (int k = 0; k < m; k += 8) {
                int c0 = __shfl(cl, k),     c1 = __shfl(cl, k + 1);
                int c2 = __shfl(cl, k + 2), c3 = __shfl(cl, k + 3);
                int c4 = __shfl(cl, k + 4), c5 = __shfl(cl, k + 5);
                int c6 = __shfl(cl, k + 6), c7 = __shfl(cl, k + 7);
                float w0 = __shfl(wl, k),     w1 = __shfl(wl, k + 1);
                float w2 = __shfl(wl, k + 2), w3 = __shfl(wl, k + 3);
                float w4 = __shfl(wl, k + 4), w5 = __shfl(wl, k + 5);
                float w6 = __shfl(wl, k + 6), w7 = __shfl(wl, k + 7);
                unsigned int v0 = xb2[(size_t)c0 * 64 + lane];
                unsigned int v1 = xb2[(size_t)c1 * 64 + lane];
                unsigned int v2 = xb2[(size_t)c2 * 64 + lane];
                unsigned int v3 = xb2[(size_t)c3 * 64 + lane];
                unsigned int v4 = xb2[(size_t)c4 * 64 + lane];
                unsigned int v5 = xb2[(size_t)c5 * 64 + lane];
                unsigned int v6 = xb2[(size_t)c6 * 64 + lane];
                unsigned int v7 = xb2[(size_t)c7 * 64 + lane];
                ax += w0 * bflo(v0) + w1 * bflo(v1) + w2 * bflo(v2) + w3 * bflo(v3)
                    + w4 * bflo(v4) + w5 * bflo(v5) + w6 * bflo(v6) + w7 * bflo(v7);
                ay += w0 * bfhi(v0) + w1 * bfhi(v1) + w2 * bfhi(v2) + w3 * bfhi(v3)
                    + w4 * bfhi(v4) + w5 * bfhi(v5) + w6 * bfhi(v6) + w7 * bfhi(v7);
            }
        }
        unsigned int v = xb2[(size_t)node * 64 + lane];
        ax = di * ax + di * di * bflo(v);
        ay = di * ay + di * di * bfhi(v);
        *(float2*)&out[(size_t)node * 128 + 2 * lane] = make_float2(ax, ay);
    }
}

// ------- GEMM (+bias+relu): out[N,128] = A[N,K] @ W[K,128], optional bf16 out -------

template <int K, bool OUTBF>
__global__ __launch_bounds__(256) void k_gemm_relu(
    const float* __restrict__ A, const float* __restrict__ W,
    const float* __restrict__ bias, void* __restrict__ outp, int N) {
    __shared__ float Wlds[64][128];
    int tid = threadIdx.x;
    int rg = tid >> 3;   // 0..31
    int cg = tid & 7;    // 0..7 -> cols [cg*16, cg*16+16)
    int row0 = blockIdx.x * 128 + rg * 4;

    float4 acc[4][4];
#pragma unroll
    for (int i = 0; i < 4; ++i)
#pragma unroll
        for (int j = 0; j < 4; ++j) acc[i][j] = make_float4(0.f, 0.f, 0.f, 0.f);

    for (int kc = 0; kc < K; kc += 64) {
        const float4* wsrc = (const float4*)(W + (size_t)kc * 128);
        float4* wdst = (float4*)Wlds;
        for (int t = tid; t < 2048; t += 256) wdst[t] = wsrc[t];
        __syncthreads();

        for (int k4 = 0; k4 < 64; k4 += 4) {
            float4 av[4];
#pragma unroll
            for (int i = 0; i < 4; ++i) {
                int r = row0 + i;
                if (r >= N) r = N - 1;
                av[i] = *(const float4*)&A[(size_t)r * K + kc + k4];
            }
#pragma unroll
            for (int kk = 0; kk < 4; ++kk) {
                float4 w[4];
#pragma unroll
                for (int j = 0; j < 4; ++j)
                    w[j] = *(const float4*)&Wlds[k4 + kk][cg * 16 + 4 * j];
#pragma unroll
                for (int i = 0; i < 4; ++i) {
                    float a = (kk == 0) ? av[i].x : (kk == 1) ? av[i].y
                              : (kk == 2) ? av[i].z : av[i].w;
#pragma unroll
                    for (int j = 0; j < 4; ++j) {
                        acc[i][j].x += a * w[j].x;
                        acc[i][j].y += a * w[j].y;
                        acc[i][j].z += a * w[j].z;
                        acc[i][j].w += a * w[j].w;
                    }
                }
            }
        }
        __syncthreads();
    }

#pragma unroll
    for (int j = 0; j < 4; ++j) {
        float4 bv = *(const float4*)&bias[cg * 16 + 4 * j];
#pragma unroll
        for (int i = 0; i < 4; ++i) {
            int r = row0 + i;
            if (r < N) {
                float ox = fmaxf(acc[i][j].x + bv.x, 0.f);
                float oy = fmaxf(acc[i][j].y + bv.y, 0.f);
                float oz = fmaxf(acc[i][j].z + bv.z, 0.f);
                float ow = fmaxf(acc[i][j].w + bv.w, 0.f);
                if constexpr (OUTBF) {
                    ushort4 o;
                    o.x = f2bf(ox); o.y = f2bf(oy); o.z = f2bf(oz); o.w = f2bf(ow);
                    *(ushort4*)&((unsigned short*)outp)[(size_t)r * 128 + cg * 16 + 4 * j] = o;
                } else {
                    float4 o = make_float4(ox, oy, oz, ow);
                    *(float4*)&((float*)outp)[(size_t)r * 128 + cg * 16 + 4 * j] = o;
                }
            }
        }
    }
}

// ---------------- pooling ----------------

__global__ void k_cntg_bs(const int* __restrict__ batch, int* __restrict__ cntg, int N) {
    int g = threadIdx.x;
    if (g >= 64) return;
    int lo = 0, hi = N;
    while (lo < hi) { int mid = (lo + hi) >> 1; if (batch[mid] < g) lo = mid + 1; else hi = mid; }
    int start = lo;
    lo = 0; hi = N;
    while (lo < hi) { int mid = (lo + hi) >> 1; if (batch[mid] < g + 1) lo = mid + 1; else hi = mid; }
    cntg[g] = lo - start;
}

#define POOL_NPB 64
__global__ void k_pool(const float* __restrict__ h, const int* __restrict__ batch,
                       float* __restrict__ pooled, int N) {
    int tid = threadIdx.x;  // 128 threads = channel
    int start = blockIdx.x * POOL_NPB;
    int end = start + POOL_NPB;
    if (end > N) end = N;
    if (start >= end) return;
    int curg = batch[start];
    float acc = 0.f;
    for (int n = start; n < end; ++n) {
        int g = batch[n];
        if (g != curg) {
            atomicAdd(&pooled[curg * 128 + tid], acc);
            acc = 0.f;
            curg = g;
        }
        acc += h[(size_t)n * 128 + tid];
    }
    atomicAdd(&pooled[curg * 128 + tid], acc);
}

__global__ void k_final(const float* __restrict__ pooled, const int* __restrict__ cntg,
                        const float* __restrict__ Wc, const float* __restrict__ bc,
                        float* __restrict__ out) {
    for (int idx = threadIdx.x; idx < 64 * 10; idx += 256) {
        int g = idx / 10, c = idx % 10;
        float s = 0.f;
        for (int k = 0; k < 128; ++k) s += pooled[g * 128 + k] * Wc[k * 10 + c];
        float cnt = (float)cntg[g];
        if (cnt < 1.f) cnt = 1.f;
        out[idx] = s / cnt + bc[c];
    }
}

// ---------------- launch ----------------

extern "C" void kernel_launch(void* const* d_in, const int* in_sizes, int n_in,
                              void* d_out, int out_size, void* d_ws, size_t ws_size,
                              hipStream_t stream) {
    const float* x  = (const float*)d_in[0];
    const float* W1 = (const float*)d_in[1];
    const float* b1 = (const float*)d_in[2];
    const float* W2 = (const float*)d_in[3];
    const float* b2 = (const float*)d_in[4];
    const float* Wc = (const float*)d_in[5];
    const float* bc = (const float*)d_in[6];
    const int* ei   = (const int*)d_in[7];
    const int* batch = (const int*)d_in[8];

    const int E = in_sizes[7] / 2;
    const int N = in_sizes[8];
    const int* src = ei;
    const int* dst = ei + E;

    char* p = (char*)d_ws;
    auto alloc = [&](size_t bytes) -> void* {
        void* r = (void*)p;
        p += (bytes + 255) & ~(size_t)255;
        return r;
    };
    int*   cnt      = (int*)alloc((size_t)N * 4);
    float* dinv     = (float*)alloc((size_t)N * 4);
    int*   row_ptr  = (int*)alloc((size_t)(N + 1) * 4);
    int*   fill_ptr = (int*)alloc((size_t)N * 4);
    int*   bsums    = (int*)alloc(4096);
    int*   col      = (int*)alloc((size_t)E * 4);
    unsigned short* xb  = (unsigned short*)alloc((size_t)N * 64 * 2);
    unsigned short* h1b = (unsigned short*)alloc((size_t)N * 128 * 2);
    float* bufA     = (float*)alloc((size_t)N * 128 * 4);
    float* bufB     = (float*)alloc((size_t)N * 128 * 4);
    float* pooled   = (float*)alloc(64 * 128 * 4);
    int*   cntg     = (int*)alloc(64 * 4);

    hipMemsetAsync(cnt, 0, (size_t)N * 4, stream);
    hipMemsetAsync(pooled, 0, 64 * 128 * 4, stream);

    int nb = (N + 511) / 512;

    k_deg_count<<<(E + 255) / 256, 256, 0, stream>>>(dst, cnt, E);
    k_dinv<<<(N + 255) / 256, 256, 0, stream>>>(cnt, dinv, N);
    k_scan1<<<nb, 512, 0, stream>>>(cnt, row_ptr, bsums, N);
    k_scan2<<<1, 64, 0, stream>>>(bsums, nb);
    k_scan3<<<(N + 255) / 256, 256, 0, stream>>>(row_ptr, fill_ptr, bsums, N, E);
    k_fill<<<512, 256, 0, stream>>>(src, dst, fill_ptr, col, E, N);

    // x -> bf16 (gather operand for layer 1)
    k_tobf16<<<(N * 64 / 8 + 255) / 256, 256, 0, stream>>>(x, xb, N * 64 / 8);

    // layer 1: aggregate x_bf16 (64 ch) then transform; h1 written as bf16
    k_agg<64><<<(N + 3) / 4, 256, 0, stream>>>(xb, row_ptr, col, dinv, bufA, N);
    k_gemm_relu<64, true><<<(N + 127) / 128, 256, 0, stream>>>(bufA, W1, b1, h1b, N);

    // layer 2: aggregate h1_bf16 (128 ch) then transform (f32 out)
    k_agg<128><<<(N + 3) / 4, 256, 0, stream>>>(h1b, row_ptr, col, dinv, bufA, N);
    k_gemm_relu<128, false><<<(N + 127) / 128, 256, 0, stream>>>(bufA, W2, b2, bufB, N);

    // pool + classify
    k_cntg_bs<<<1, 64, 0, stream>>>(batch, cntg, N);
    k_pool<<<(N + POOL_NPB - 1) / POOL_NPB, 128, 0, stream>>>(bufB, batch, pooled, N);
    k_final<<<1, 256, 0, stream>>>(pooled, cntg, Wc, bc, (float*)d_out);
}

// Round 8
// 389.723 us; speedup vs baseline: 1.1872x; 1.1521x over previous
//
#include <hip/hip_runtime.h>

#define NN 100000
#define NE 1600000

using half8 = __attribute__((ext_vector_type(8))) _Float16;
using f32x4 = __attribute__((ext_vector_type(4))) float;

// ---- bf16 helpers (round-to-nearest-even, matches numpy/jax cast) ----
__device__ inline unsigned short f2bf(float f) {
    unsigned int u = __float_as_uint(f);
    unsigned int r = (u + 0x7fffu + ((u >> 16) & 1u)) >> 16;
    return (unsigned short)r;
}
__device__ inline float bf2f(unsigned short h) {
    return __uint_as_float(((unsigned int)h) << 16);
}
__device__ inline float bflo(unsigned int v) { return __uint_as_float(v << 16); }
__device__ inline float bfhi(unsigned int v) { return __uint_as_float(v & 0xffff0000u); }
__device__ inline unsigned short f2h(float f) {
    union { _Float16 h; unsigned short u; } c; c.h = (_Float16)f; return c.u;
}

// ---------------- CSR build ----------------

__global__ void k_deg_count(const int* __restrict__ dst, int* __restrict__ cnt, int E) {
    int e = blockIdx.x * blockDim.x + threadIdx.x;
    if (e < E) atomicAdd(&cnt[dst[e]], 1);
}

__global__ void k_dinv(const int* __restrict__ cnt, float* __restrict__ dinv, int N) {
    int i = blockIdx.x * blockDim.x + threadIdx.x;
    if (i < N) dinv[i] = rsqrtf((float)(cnt[i] + 1));  // +1 self loop
}

__global__ void k_scan1(const int* __restrict__ cnt, int* __restrict__ excl,
                        int* __restrict__ bsums, int N) {
    __shared__ int s[512];
    int tid = threadIdx.x;
    int i = blockIdx.x * 512 + tid;
    int v = (i < N) ? cnt[i] : 0;
    s[tid] = v;
    __syncthreads();
    for (int off = 1; off < 512; off <<= 1) {
        int t = (tid >= off) ? s[tid - off] : 0;
        __syncthreads();
        s[tid] += t;
        __syncthreads();
    }
    if (i < N) excl[i] = s[tid] - v;
    if (tid == 511) bsums[blockIdx.x] = s[511];
}

__global__ void k_scan2(int* __restrict__ bsums, int nb) {
    if (blockIdx.x == 0 && threadIdx.x == 0) {
        int run = 0;
        for (int b = 0; b < nb; ++b) { int t = bsums[b]; bsums[b] = run; run += t; }
    }
}

__global__ void k_scan3(int* __restrict__ row_ptr, int* __restrict__ fill_ptr,
                        const int* __restrict__ bsums, int N, int E) {
    int i = blockIdx.x * blockDim.x + threadIdx.x;
    if (i < N) {
        int v = row_ptr[i] + bsums[i >> 9];
        row_ptr[i] = v;
        fill_ptr[i] = v;
    }
    if (i == 0) row_ptr[N] = E;
}

#define FILL_RANGES 8
__global__ void k_fill(const int* __restrict__ src, const int* __restrict__ dst,
                       int* __restrict__ fill_ptr, int* __restrict__ col, int E, int N) {
    int range  = blockIdx.x & (FILL_RANGES - 1);
    int chunkI = blockIdx.x >> 3;
    int nchunk = gridDim.x >> 3;
    int per = (E + nchunk - 1) / nchunk;
    int e0 = chunkI * per;
    int e1 = e0 + per; if (e1 > E) e1 = E;
    int rng = (N + FILL_RANGES - 1) / FILL_RANGES;
    int dlo = range * rng, dhi = dlo + rng;
    for (int e = e0 + threadIdx.x; e < e1; e += blockDim.x) {
        int d = dst[e];
        if (d >= dlo && d < dhi) {
            int pos = atomicAdd(&fill_ptr[d], 1);
            col[pos] = src[e];
        }
    }
}

// ---------------- f32 -> bf16 conversion (8 elems/thread) ----------------

__global__ void k_tobf16(const float* __restrict__ in, unsigned short* __restrict__ out, int n8) {
    int i = blockIdx.x * blockDim.x + threadIdx.x;
    if (i >= n8) return;
    const float4* p = (const float4*)(in + (size_t)i * 8);
    float4 a = p[0], b = p[1];
    uint4 o;
    o.x = (unsigned)f2bf(a.x) | ((unsigned)f2bf(a.y) << 16);
    o.y = (unsigned)f2bf(a.z) | ((unsigned)f2bf(a.w) << 16);
    o.z = (unsigned)f2bf(b.x) | ((unsigned)f2bf(b.y) << 16);
    o.w = (unsigned)f2bf(b.z) | ((unsigned)f2bf(b.w) << 16);
    ((uint4*)out)[i] = o;
}

// ---- pack W[K,128] f32 into f16 fragment-major layout for mfma_16x16x32 ----
// wpack[(s*8+j)*64 + l][jj] = W[32*s + 8*(l>>4) + jj][16*j + (l&15)]
__global__ void k_packW(const float* __restrict__ W, half8* __restrict__ wpack, int K) {
    int t = blockIdx.x * blockDim.x + threadIdx.x;
    int total = (K / 32) * 8 * 64;
    if (t >= total) return;
    int s = t >> 9;
    int j = (t >> 6) & 7;
    int l = t & 63;
    half8 hv;
#pragma unroll
    for (int jj = 0; jj < 8; ++jj)
        hv[jj] = (_Float16)W[(size_t)(32 * s + 8 * (l >> 4) + jj) * 128 + 16 * j + (l & 15)];
    wpack[t] = hv;
}

// ------- aggregation: wave/node; coalesced col staging, dinv gathered (L2-hit),
// ------- dinv[node] factored out; 8 row-gathers in flight; f16 output -------

template <int C>
__global__ void k_agg(const unsigned short* __restrict__ xb, const int* __restrict__ row_ptr,
                      const int* __restrict__ col, const float* __restrict__ dinv,
                      unsigned short* __restrict__ out, int N) {
    int node = blockIdx.x * (blockDim.x >> 6) + (threadIdx.x >> 6);
    int lane = threadIdx.x & 63;
    if (node >= N) return;
    int beg = row_ptr[node], end = row_ptr[node + 1];
    float di = dinv[node];

    if constexpr (C == 64) {
        float acc = 0.f;
        for (int base = beg; base < end; base += 64) {
            int m = end - base; if (m > 64) m = 64;
            int sel = (lane < m) ? lane : (m - 1);
            int cl = col[base + sel];
            float wl = (lane < m) ? dinv[cl] : 0.f;
            for (int k = 0; k < m; k += 8) {
                int c0 = __shfl(cl, k),     c1 = __shfl(cl, k + 1);
                int c2 = __shfl(cl, k + 2), c3 = __shfl(cl, k + 3);
                int c4 = __shfl(cl, k + 4), c5 = __shfl(cl, k + 5);
                int c6 = __shfl(cl, k + 6), c7 = __shfl(cl, k + 7);
                float w0 = __shfl(wl, k),     w1 = __shfl(wl, k + 1);
                float w2 = __shfl(wl, k + 2), w3 = __shfl(wl, k + 3);
                float w4 = __shfl(wl, k + 4), w5 = __shfl(wl, k + 5);
                float w6 = __shfl(wl, k + 6), w7 = __shfl(wl, k + 7);
                unsigned short v0 = xb[(size_t)c0 * 64 + lane];
                unsigned short v1 = xb[(size_t)c1 * 64 + lane];
                unsigned short v2 = xb[(size_t)c2 * 64 + lane];
                unsigned short v3 = xb[(size_t)c3 * 64 + lane];
                unsigned short v4 = xb[(size_t)c4 * 64 + lane];
                unsigned short v5 = xb[(size_t)c5 * 64 + lane];
                unsigned short v6 = xb[(size_t)c6 * 64 + lane];
                unsigned short v7 = xb[(size_t)c7 * 64 + lane];
                acc += w0 * bf2f(v0) + w1 * bf2f(v1) + w2 * bf2f(v2) + w3 * bf2f(v3)
                     + w4 * bf2f(v4) + w5 * bf2f(v5) + w6 * bf2f(v6) + w7 * bf2f(v7);
            }
        }
        acc = di * acc + di * di * bf2f(xb[(size_t)node * 64 + lane]);
        out[(size_t)node * 64 + lane] = f2h(acc);
    } else {
        const unsigned int* xb2 = (const unsigned int*)xb;  // 2 bf16 per uint
        float ax = 0.f, ay = 0.f;
        for (int base = beg; base < end; base += 64) {
            int m = end - base; if (m > 64) m = 64;
            int sel = (lane < m) ? lane : (m - 1);
            int cl = col[base + sel];
            float wl = (lane < m) ? dinv[cl] : 0.f;
            for (int k = 0; k < m; k += 8) {
                int c0 = __shfl(cl, k),     c1 = __shfl(cl, k + 1);
                int c2 = __shfl(cl, k + 2), c3 = __shfl(cl, k + 3);
                int c4 = __shfl(cl, k + 4), c5 = __shfl(cl, k + 5);
                int c6 = __shfl(cl, k + 6), c7 = __shfl(cl, k + 7);
                float w0 = __shfl(wl, k),     w1 = __shfl(wl, k + 1);
                float w2 = __shfl(wl, k + 2), w3 = __shfl(wl, k + 3);
                float w4 = __shfl(wl, k + 4), w5 = __shfl(wl, k + 5);
                float w6 = __shfl(wl, k + 6), w7 = __shfl(wl, k + 7);
                unsigned int v0 = xb2[(size_t)c0 * 64 + lane];
                unsigned int v1 = xb2[(size_t)c1 * 64 + lane];
                unsigned int v2 = xb2[(size_t)c2 * 64 + lane];
                unsigned int v3 = xb2[(size_t)c3 * 64 + lane];
                unsigned int v4 = xb2[(size_t)c4 * 64 + lane];
                unsigned int v5 = xb2[(size_t)c5 * 64 + lane];
                unsigned int v6 = xb2[(size_t)c6 * 64 + lane];
                unsigned int v7 = xb2[(size_t)c7 * 64 + lane];
                ax += w0 * bflo(v0) + w1 * bflo(v1) + w2 * bflo(v2) + w3 * bflo(v3)
                    + w4 * bflo(v4) + w5 * bflo(v5) + w6 * bflo(v6) + w7 * bflo(v7);
                ay += w0 * bfhi(v0) + w1 * bfhi(v1) + w2 * bfhi(v2) + w3 * bfhi(v3)
                    + w4 * bfhi(v4) + w5 * bfhi(v5) + w6 * bfhi(v6) + w7 * bfhi(v7);
            }
        }
        unsigned int v = xb2[(size_t)node * 64 + lane];
        ax = di * ax + di * di * bflo(v);
        ay = di * ay + di * di * bfhi(v);
        ((unsigned int*)out)[(size_t)node * 64 + lane] =
            (unsigned int)f2h(ax) | ((unsigned int)f2h(ay) << 16);
    }
}

// ------- MFMA GEMM (+bias+relu): out[N,128] = A[N,K](f16) @ W[K,128](f16) -------
// 4 waves/block, wave handles 16 rows x 128 cols. C/D layout (m89-verified):
// col = lane&15, row = (lane>>4)*4 + reg.

template <int K, bool OUTBF>
__global__ __launch_bounds__(256) void k_gemm_mfma(
    const unsigned short* __restrict__ A, const half8* __restrict__ wpack,
    const float* __restrict__ bias, void* __restrict__ outp, int N) {
    int lane = threadIdx.x & 63;
    int wave = threadIdx.x >> 6;
    int row0 = blockIdx.x * 64 + wave * 16;
    int ar = row0 + (lane & 15);
    if (ar >= N) ar = N - 1;
    const _Float16* Ah = (const _Float16*)A;

    f32x4 acc[8];
#pragma unroll
    for (int j = 0; j < 8; ++j) acc[j] = (f32x4)(0.f);

#pragma unroll
    for (int s = 0; s < K / 32; ++s) {
        half8 av = *(const half8*)(Ah + (size_t)ar * K + 32 * s + 8 * (lane >> 4));
#pragma unroll
        for (int j = 0; j < 8; ++j) {
            half8 bv = wpack[(s * 8 + j) * 64 + lane];
            acc[j] = __builtin_amdgcn_mfma_f32_16x16x32_f16(av, bv, acc[j], 0, 0, 0);
        }
    }

    int rowb = row0 + (lane >> 4) * 4;
#pragma unroll
    for (int j = 0; j < 8; ++j) {
        int colc = j * 16 + (lane & 15);
        float b = bias[colc];
#pragma unroll
        for (int r = 0; r < 4; ++r) {
            int rr = rowb + r;
            if (rr < N) {
                float v = fmaxf(acc[j][r] + b, 0.f);
                if constexpr (OUTBF)
                    ((unsigned short*)outp)[(size_t)rr * 128 + colc] = f2bf(v);
                else
                    ((float*)outp)[(size_t)rr * 128 + colc] = v;
            }
        }
    }
}

// ---------------- pooling ----------------

__global__ void k_cntg_bs(const int* __restrict__ batch, int* __restrict__ cntg, int N) {
    int g = threadIdx.x;
    if (g >= 64) return;
    int lo = 0, hi = N;
    while (lo < hi) { int mid = (lo + hi) >> 1; if (batch[mid] < g) lo = mid + 1; else hi = mid; }
    int start = lo;
    lo = 0; hi = N;
    while (lo < hi) { int mid = (lo + hi) >> 1; if (batch[mid] < g + 1) lo = mid + 1; else hi = mid; }
    cntg[g] = lo - start;
}

#define POOL_NPB 64
__global__ void k_pool(const float* __restrict__ h, const int* __restrict__ batch,
                       float* __restrict__ pooled, int N) {
    int tid = threadIdx.x;  // 128 threads = channel
    int start = blockIdx.x * POOL_NPB;
    int end = start + POOL_NPB;
    if (end > N) end = N;
    if (start >= end) return;
    int curg = batch[start];
    float acc = 0.f;
    for (int n = start; n < end; ++n) {
        int g = batch[n];
        if (g != curg) {
            atomicAdd(&pooled[curg * 128 + tid], acc);
            acc = 0.f;
            curg = g;
        }
        acc += h[(size_t)n * 128 + tid];
    }
    atomicAdd(&pooled[curg * 128 + tid], acc);
}

__global__ void k_final(const float* __restrict__ pooled, const int* __restrict__ cntg,
                        const float* __restrict__ Wc, const float* __restrict__ bc,
                        float* __restrict__ out) {
    for (int idx = threadIdx.x; idx < 64 * 10; idx += 256) {
        int g = idx / 10, c = idx % 10;
        float s = 0.f;
        for (int k = 0; k < 128; ++k) s += pooled[g * 128 + k] * Wc[k * 10 + c];
        float cnt = (float)cntg[g];
        if (cnt < 1.f) cnt = 1.f;
        out[idx] = s / cnt + bc[c];
    }
}

// ---------------- launch ----------------

extern "C" void kernel_launch(void* const* d_in, const int* in_sizes, int n_in,
                              void* d_out, int out_size, void* d_ws, size_t ws_size,
                              hipStream_t stream) {
    const float* x  = (const float*)d_in[0];
    const float* W1 = (const float*)d_in[1];
    const float* b1 = (const float*)d_in[2];
    const float* W2 = (const float*)d_in[3];
    const float* b2 = (const float*)d_in[4];
    const float* Wc = (const float*)d_in[5];
    const float* bc = (const float*)d_in[6];
    const int* ei   = (const int*)d_in[7];
    const int* batch = (const int*)d_in[8];

    const int E = in_sizes[7] / 2;
    const int N = in_sizes[8];
    const int* src = ei;
    const int* dst = ei + E;

    char* p = (char*)d_ws;
    auto alloc = [&](size_t bytes) -> void* {
        void* r = (void*)p;
        p += (bytes + 255) & ~(size_t)255;
        return r;
    };
    int*   cnt      = (int*)alloc((size_t)N * 4);
    float* dinv     = (float*)alloc((size_t)N * 4);
    int*   row_ptr  = (int*)alloc((size_t)(N + 1) * 4);
    int*   fill_ptr = (int*)alloc((size_t)N * 4);
    int*   bsums    = (int*)alloc(4096);
    int*   col      = (int*)alloc((size_t)E * 4);
    unsigned short* xb    = (unsigned short*)alloc((size_t)N * 64 * 2);
    unsigned short* h1b   = (unsigned short*)alloc((size_t)N * 128 * 2);
    unsigned short* aggb1 = (unsigned short*)alloc((size_t)N * 64 * 2);
    unsigned short* aggb2 = (unsigned short*)alloc((size_t)N * 128 * 2);
    half8* w1p      = (half8*)alloc(1024 * 16);
    half8* w2p      = (half8*)alloc(2048 * 16);
    float* bufB     = (float*)alloc((size_t)N * 128 * 4);
    float* pooled   = (float*)alloc(64 * 128 * 4);
    int*   cntg     = (int*)alloc(64 * 4);

    hipMemsetAsync(cnt, 0, (size_t)N * 4, stream);
    hipMemsetAsync(pooled, 0, 64 * 128 * 4, stream);

    int nb = (N + 511) / 512;

    k_deg_count<<<(E + 255) / 256, 256, 0, stream>>>(dst, cnt, E);
    k_dinv<<<(N + 255) / 256, 256, 0, stream>>>(cnt, dinv, N);
    k_scan1<<<nb, 512, 0, stream>>>(cnt, row_ptr, bsums, N);
    k_scan2<<<1, 64, 0, stream>>>(bsums, nb);
    k_scan3<<<(N + 255) / 256, 256, 0, stream>>>(row_ptr, fill_ptr, bsums, N, E);
    k_fill<<<512, 256, 0, stream>>>(src, dst, fill_ptr, col, E, N);

    // weight packs + x -> bf16
    k_packW<<<4, 256, 0, stream>>>(W1, w1p, 64);
    k_packW<<<8, 256, 0, stream>>>(W2, w2p, 128);
    k_tobf16<<<(N * 64 / 8 + 255) / 256, 256, 0, stream>>>(x, xb, N * 64 / 8);

    // layer 1: aggregate x_bf16 (64 ch) -> f16, MFMA transform -> h1 bf16
    k_agg<64><<<(N + 3) / 4, 256, 0, stream>>>(xb, row_ptr, col, dinv, aggb1, N);
    k_gemm_mfma<64, true><<<(N + 63) / 64, 256, 0, stream>>>(aggb1, w1p, b1, h1b, N);

    // layer 2: aggregate h1_bf16 (128 ch) -> f16, MFMA transform -> f32
    k_agg<128><<<(N + 3) / 4, 256, 0, stream>>>(h1b, row_ptr, col, dinv, aggb2, N);
    k_gemm_mfma<128, false><<<(N + 63) / 64, 256, 0, stream>>>(aggb2, w2p, b2, bufB, N);

    // pool + classify
    k_cntg_bs<<<1, 64, 0, stream>>>(batch, cntg, N);
    k_pool<<<(N + POOL_NPB - 1) / POOL_NPB, 128, 0, stream>>>(bufB, batch, pooled, N);
    k_final<<<1, 256, 0, stream>>>(pooled, cntg, Wc, bc, (float*)d_out);
}